// Round 1
// baseline (339.853 us; speedup 1.0000x reference)
//
#include <hip/hip_runtime.h>

// DGCNN forward, fully fused: one workgroup per graph, all state in LDS.
// B=512 graphs, M=200 nodes, 6400 edges/graph (block-contiguous), F_in=128.
// All pre-sort math in f32 (sort-key tie sensitivity). No workspace needed.

#define TPB   1024
#define GRID  512
#define MG    200
#define EPG   6400
#define EE    (512 * EPG)

// ---- LDS layout (byte offsets). Total 150,272 B (<= 160 KiB/CU, 1 block/CU) ----
#define OFF_H1   0        // f32[200*36]  h1
#define OFF_H2   28800    // f32[200*36]  h2
#define OFF_H3   57600    // f32[200*36]  h3
#define OFF_BUFX 86400    // f32[200*36]  xw (scaled by dinv[src]); later: top[30][100]
#define OFF_WREG 115200   // f32[4160]    W of current layer; later convW1|convW2
#define OFF_CSR  131840   // u16[6600]    CSR src-local ids (incl. self-loop entry)
#define OFF_ROFF 145040   // i32[201]     row offsets (+4 pad)
#define OFF_CUR  145848   // i32[200]     placement cursors
#define OFF_CNT  146648   // i32[200]     in-degree counts
#define OFF_DINV 147448   // f32[200]
#define OFF_H4   148248   // f32[200]     sort key (h4)
#define OFF_RANK 149048   // i32[200]
#define OFF_ORD  149848   // i32[30]
#define OFF_BIAS 149968   // f32[48]      layer bias / convb1+convb2
#define OFF_RED  150160   // f32[16]
#define SMEM_BYTES 150272

__global__ __launch_bounds__(TPB) void dgcnn_kernel(
    const float* __restrict__ x,
    const int*   __restrict__ ei,
    const float* __restrict__ W1, const float* __restrict__ b1,
    const float* __restrict__ W2, const float* __restrict__ b2,
    const float* __restrict__ W3, const float* __restrict__ b3,
    const float* __restrict__ W4, const float* __restrict__ b4,
    const float* __restrict__ cW1, const float* __restrict__ cb1,
    const float* __restrict__ cW2, const float* __restrict__ cb2,
    const float* __restrict__ lW1, const float* __restrict__ lb1,
    const float* __restrict__ lW2, const float* __restrict__ lb2,
    float* __restrict__ out)
{
    extern __shared__ unsigned char smem[];
    float* h1b  = (float*)(smem + OFF_H1);
    float* h2b  = (float*)(smem + OFF_H2);
    float* h3b  = (float*)(smem + OFF_H3);
    float* bufX = (float*)(smem + OFF_BUFX);
    float* wreg = (float*)(smem + OFF_WREG);
    unsigned short* csr = (unsigned short*)(smem + OFF_CSR);
    int*   roff = (int*)(smem + OFF_ROFF);
    int*   cur  = (int*)(smem + OFF_CUR);
    int*   cnt  = (int*)(smem + OFF_CNT);
    float* dinv = (float*)(smem + OFF_DINV);
    float* h4k  = (float*)(smem + OFF_H4);
    int*   rank = (int*)(smem + OFF_RANK);
    int*   ord  = (int*)(smem + OFF_ORD);
    float* bias = (float*)(smem + OFF_BIAS);
    float* red  = (float*)(smem + OFF_RED);

    const int g = blockIdx.x;
    const int t = threadIdx.x;
    const int gbase = g * MG;
    const float* xg   = x + (size_t)gbase * 128;
    const int*   srcp = ei + (size_t)g * EPG;
    const int*   dstp = ei + (size_t)EE + (size_t)g * EPG;

    // ---------------- Phase A: stage W1/b1, zero counters ----------------
    for (int idx = t; idx < 4096; idx += TPB) wreg[idx] = W1[idx];
    if (t < 32) bias[t] = b1[t];
    if (t < MG) { cnt[t] = 0; rank[t] = 0; }
    __syncthreads();

    // ---------------- Phase B: in-degree count ----------------
    for (int e = t; e < EPG; e += TPB) {
        int d = dstp[e] - gbase;
        atomicAdd(&cnt[d], 1);
    }
    __syncthreads();

    // ---------------- Phase C: dinv + prefix scan (row length = cnt+1, self-loop) ----
    if (t >= 256 && t < 256 + MG) {
        int i = t - 256;
        dinv[i] = 1.0f / sqrtf((float)(cnt[i] + 1));
    }
    if (t < 64) {
        if (t == 0) roff[0] = 0;
        int carry = 0;
        #pragma unroll
        for (int c = 0; c < 4; ++c) {
            const int i = c * 64 + t;
            int v = (i < MG) ? (cnt[i] + 1) : 0;
            #pragma unroll
            for (int off = 1; off < 64; off <<= 1) {
                int u = __shfl_up(v, off);
                if (t >= (int)off) v += u;
            }
            if (i < MG) roff[i + 1] = carry + v;
            carry += __shfl(v, 63);
        }
    }
    __syncthreads();

    // ---------------- Phase D: self-loop entry + cursor init ----------------
    if (t < MG) {
        int p = roff[t];
        csr[p] = (unsigned short)t;
        cur[t] = p + 1;
    }
    __syncthreads();

    // ---------------- Phase E: CSR placement ----------------
    for (int e = t; e < EPG; e += TPB) {
        int d = dstp[e] - gbase;
        int s = srcp[e] - gbase;
        int p = atomicAdd(&cur[d], 1);
        csr[p] = (unsigned short)s;
    }
    __syncthreads();

    // ---------------- GEMM helpers ----------------
    // Layer GEMM writes bufX[i][f] = dinv[i] * (row_i . W[:,f])  (dinv[src] folded in)
    const int f32lane = t & 31;
    const int islot   = t >> 5;   // 0..31

    auto agg_layer = [&](float* __restrict__ hdst) {
        // gather: hdst[d][f] = tanh(dinv[d] * sum_{p in row d} bufX[csr[p]][f] + bias[f])
        const int fq  = t & 7;
        const int f4  = fq << 2;
        const int dsl = t >> 3;   // 0..127
        for (int d = dsl; d < MG; d += 128) {
            const int p0 = roff[d], p1 = roff[d + 1];
            float a0 = 0.f, a1 = 0.f, a2 = 0.f, a3 = 0.f;
            float c0 = 0.f, c1 = 0.f, c2 = 0.f, c3 = 0.f;
            int p = p0;
            for (; p + 2 <= p1; p += 2) {
                const int s0 = csr[p], s1 = csr[p + 1];
                const float4 v0 = *(const float4*)(bufX + s0 * 36 + f4);
                const float4 v1 = *(const float4*)(bufX + s1 * 36 + f4);
                a0 += v0.x; a1 += v0.y; a2 += v0.z; a3 += v0.w;
                c0 += v1.x; c1 += v1.y; c2 += v1.z; c3 += v1.w;
            }
            if (p < p1) {
                const int s0 = csr[p];
                const float4 v0 = *(const float4*)(bufX + s0 * 36 + f4);
                a0 += v0.x; a1 += v0.y; a2 += v0.z; a3 += v0.w;
            }
            const float dv = dinv[d];
            float o0 = tanhf(dv * (a0 + c0) + bias[f4 + 0]);
            float o1 = tanhf(dv * (a1 + c1) + bias[f4 + 1]);
            float o2 = tanhf(dv * (a2 + c2) + bias[f4 + 2]);
            float o3 = tanhf(dv * (a3 + c3) + bias[f4 + 3]);
            *(float4*)(hdst + d * 36 + f4) = make_float4(o0, o1, o2, o3);
        }
    };

    auto gemm_mid = [&](const float* __restrict__ src) {
        // bufX = (src[200x32] @ W[32x32]) scaled by dinv[row]
        const int f = f32lane;
        {   // rows islot + {0,32,64,96}  (all < 200)
            float acc0 = 0.f, acc1 = 0.f, acc2 = 0.f, acc3 = 0.f;
            #pragma unroll
            for (int k4 = 0; k4 < 8; ++k4) {
                const float w0 = wreg[k4 * 128 + 0  + f];
                const float w1 = wreg[k4 * 128 + 32 + f];
                const float w2 = wreg[k4 * 128 + 64 + f];
                const float w3 = wreg[k4 * 128 + 96 + f];
                float4 v;
                v = *(const float4*)(src + (islot      ) * 36 + k4 * 4); acc0 += v.x*w0 + v.y*w1 + v.z*w2 + v.w*w3;
                v = *(const float4*)(src + (islot + 32 ) * 36 + k4 * 4); acc1 += v.x*w0 + v.y*w1 + v.z*w2 + v.w*w3;
                v = *(const float4*)(src + (islot + 64 ) * 36 + k4 * 4); acc2 += v.x*w0 + v.y*w1 + v.z*w2 + v.w*w3;
                v = *(const float4*)(src + (islot + 96 ) * 36 + k4 * 4); acc3 += v.x*w0 + v.y*w1 + v.z*w2 + v.w*w3;
            }
            bufX[(islot      ) * 36 + f] = dinv[islot      ] * acc0;
            bufX[(islot + 32 ) * 36 + f] = dinv[islot + 32 ] * acc1;
            bufX[(islot + 64 ) * 36 + f] = dinv[islot + 64 ] * acc2;
            bufX[(islot + 96 ) * 36 + f] = dinv[islot + 96 ] * acc3;
        }
        {   // rows islot + {128,160,192}; 192+islot may exceed 199
            const int i2  = islot + 192;
            const int i2c = i2 < MG ? i2 : (MG - 1);
            float acc0 = 0.f, acc1 = 0.f, acc2 = 0.f;
            #pragma unroll
            for (int k4 = 0; k4 < 8; ++k4) {
                const float w0 = wreg[k4 * 128 + 0  + f];
                const float w1 = wreg[k4 * 128 + 32 + f];
                const float w2 = wreg[k4 * 128 + 64 + f];
                const float w3 = wreg[k4 * 128 + 96 + f];
                float4 v;
                v = *(const float4*)(src + (islot + 128) * 36 + k4 * 4); acc0 += v.x*w0 + v.y*w1 + v.z*w2 + v.w*w3;
                v = *(const float4*)(src + (islot + 160) * 36 + k4 * 4); acc1 += v.x*w0 + v.y*w1 + v.z*w2 + v.w*w3;
                v = *(const float4*)(src + (i2c        ) * 36 + k4 * 4); acc2 += v.x*w0 + v.y*w1 + v.z*w2 + v.w*w3;
            }
            bufX[(islot + 128) * 36 + f] = dinv[islot + 128] * acc0;
            bufX[(islot + 160) * 36 + f] = dinv[islot + 160] * acc1;
            if (i2 < MG) bufX[i2 * 36 + f] = dinv[i2] * acc2;
        }
    };

    // ---------------- Layer 1: GEMM x[200x128] @ W1[128x32] ----------------
    {
        const int f = f32lane;
        {   // rows islot + {0,32,64,96}
            float acc0 = 0.f, acc1 = 0.f, acc2 = 0.f, acc3 = 0.f;
            const float* xr0 = xg + (islot      ) * 128;
            const float* xr1 = xg + (islot + 32 ) * 128;
            const float* xr2 = xg + (islot + 64 ) * 128;
            const float* xr3 = xg + (islot + 96 ) * 128;
            #pragma unroll 4
            for (int k4 = 0; k4 < 32; ++k4) {
                const float w0 = wreg[k4 * 128 + 0  + f];
                const float w1 = wreg[k4 * 128 + 32 + f];
                const float w2 = wreg[k4 * 128 + 64 + f];
                const float w3 = wreg[k4 * 128 + 96 + f];
                float4 v;
                v = *(const float4*)(xr0 + k4 * 4); acc0 += v.x*w0 + v.y*w1 + v.z*w2 + v.w*w3;
                v = *(const float4*)(xr1 + k4 * 4); acc1 += v.x*w0 + v.y*w1 + v.z*w2 + v.w*w3;
                v = *(const float4*)(xr2 + k4 * 4); acc2 += v.x*w0 + v.y*w1 + v.z*w2 + v.w*w3;
                v = *(const float4*)(xr3 + k4 * 4); acc3 += v.x*w0 + v.y*w1 + v.z*w2 + v.w*w3;
            }
            bufX[(islot      ) * 36 + f] = dinv[islot      ] * acc0;
            bufX[(islot + 32 ) * 36 + f] = dinv[islot + 32 ] * acc1;
            bufX[(islot + 64 ) * 36 + f] = dinv[islot + 64 ] * acc2;
            bufX[(islot + 96 ) * 36 + f] = dinv[islot + 96 ] * acc3;
        }
        {   // rows islot + {128,160,192}
            const int i2  = islot + 192;
            const int i2c = i2 < MG ? i2 : (MG - 1);
            float acc0 = 0.f, acc1 = 0.f, acc2 = 0.f;
            const float* xr0 = xg + (islot + 128) * 128;
            const float* xr1 = xg + (islot + 160) * 128;
            const float* xr2 = xg + (i2c        ) * 128;
            #pragma unroll 4
            for (int k4 = 0; k4 < 32; ++k4) {
                const float w0 = wreg[k4 * 128 + 0  + f];
                const float w1 = wreg[k4 * 128 + 32 + f];
                const float w2 = wreg[k4 * 128 + 64 + f];
                const float w3 = wreg[k4 * 128 + 96 + f];
                float4 v;
                v = *(const float4*)(xr0 + k4 * 4); acc0 += v.x*w0 + v.y*w1 + v.z*w2 + v.w*w3;
                v = *(const float4*)(xr1 + k4 * 4); acc1 += v.x*w0 + v.y*w1 + v.z*w2 + v.w*w3;
                v = *(const float4*)(xr2 + k4 * 4); acc2 += v.x*w0 + v.y*w1 + v.z*w2 + v.w*w3;
            }
            bufX[(islot + 128) * 36 + f] = dinv[islot + 128] * acc0;
            bufX[(islot + 160) * 36 + f] = dinv[islot + 160] * acc1;
            if (i2 < MG) bufX[i2 * 36 + f] = dinv[i2] * acc2;
        }
    }
    __syncthreads();
    agg_layer(h1b);
    __syncthreads();

    // ---------------- Layer 2 ----------------
    for (int idx = t; idx < 1024; idx += TPB) wreg[idx] = W2[idx];
    if (t < 32) bias[t] = b2[t];
    __syncthreads();
    gemm_mid(h1b);
    __syncthreads();
    agg_layer(h2b);
    __syncthreads();

    // ---------------- Layer 3 ----------------
    for (int idx = t; idx < 1024; idx += TPB) wreg[idx] = W3[idx];
    if (t < 32) bias[t] = b3[t];
    __syncthreads();
    gemm_mid(h2b);
    __syncthreads();
    agg_layer(h3b);
    __syncthreads();

    // ---------------- Layer 4 (Fout = 1) ----------------
    if (t < MG) {
        float acc = 0.f;
        #pragma unroll 8
        for (int k = 0; k < 32; ++k) acc += h3b[t * 36 + k] * W4[k];
        bufX[t] = dinv[t] * acc;
    }
    __syncthreads();
    if (t < MG) {
        const int p0 = roff[t], p1 = roff[t + 1];
        float s = 0.f;
        for (int p = p0; p < p1; ++p) s += bufX[csr[p]];
        h4k[t] = tanhf(dinv[t] * s + b4[0]);
    }
    __syncthreads();

    // ---------------- SortPool: exact stable rank (desc value, asc index) ----------------
    if (t < 512) {
        const int i = t & 255;
        const int half = t >> 8;
        if (i < MG) {
            const float vi = h4k[i];
            int r = 0;
            const int j0 = half * 100, j1 = half * 100 + 100;
            for (int j = j0; j < j1; ++j) {
                const float vj = h4k[j];
                r += (vj > vi || (vj == vi && j < i)) ? 1 : 0;
            }
            atomicAdd(&rank[i], r);
        }
    }
    __syncthreads();
    if (t < MG) {
        const int r = rank[t];
        if (r < 30) ord[r] = t;
    }
    __syncthreads();

    // ---------------- Stage conv weights + gather top-30 features ----------------
    float* topv = bufX;   // [30][100]
    for (int idx = t; idx < 16 * 97; idx += TPB) wreg[idx] = cW1[idx];
    for (int idx = t; idx < 32 * 80; idx += TPB) wreg[1552 + idx] = cW2[idx];
    if (t < 16) bias[t] = cb1[t];
    else if (t < 48) bias[t] = cb2[t - 16];
    for (int idx = t; idx < 30 * 97; idx += TPB) {
        const int kk = idx / 97;
        const int f  = idx - kk * 97;
        const int nd = ord[kk];
        float v;
        if      (f < 32) v = h1b[nd * 36 + f];
        else if (f < 64) v = h2b[nd * 36 + (f - 32)];
        else if (f < 96) v = h3b[nd * 36 + (f - 64)];
        else             v = h4k[nd];
        topv[kk * 100 + f] = v;
    }
    __syncthreads();

    // conv scratch aliases (h1b free after top staged)
    float* c1   = h1b;            // [16][30]
    float* c1p  = h1b + 480;      // [16][16]
    float* flat = h1b + 736;      // [352]
    float* hlin = h1b + 1088;     // [128]

    // ---------------- Conv1 (per-slot linear 97->16) + ReLU ----------------
    if (t < 480) {
        const int o  = t & 15;
        const int tt = t >> 4;
        float a = bias[o];
        const float* wrow = wreg + o * 97;
        const float* trow = topv + tt * 100;
        #pragma unroll 4
        for (int f = 0; f < 97; ++f) a += wrow[f] * trow[f];
        c1[o * 30 + tt] = fmaxf(a, 0.f);
    }
    __syncthreads();

    // ---------------- MaxPool1d(2,2): 30 -> 15 ----------------
    if (t < 240) {
        const int o  = t & 15;
        const int tp = t >> 4;
        c1p[o * 16 + tp] = fmaxf(c1[o * 30 + 2 * tp], c1[o * 30 + 2 * tp + 1]);
    }
    __syncthreads();

    // ---------------- Conv2 (16->32, k=5) + ReLU -> flat[352]; init hlin ----------------
    if (t < 352) {
        const int o  = t & 31;
        const int tt = t >> 5;   // 0..10
        float a = bias[16 + o];
        const float* w2r = wreg + 1552 + o * 80;
        #pragma unroll
        for (int i2 = 0; i2 < 16; ++i2) {
            #pragma unroll
            for (int kk = 0; kk < 5; ++kk)
                a += w2r[i2 * 5 + kk] * c1p[i2 * 16 + tt + kk];
        }
        flat[o * 11 + tt] = fmaxf(a, 0.f);
    } else if (t >= 512 && t < 640) {
        hlin[t - 512] = lb1[t - 512];
    }
    __syncthreads();

    // ---------------- Linear 352->128 (split-K over 8 groups) ----------------
    {
        const int f  = t & 127;
        const int kc = t >> 7;   // 0..7, 44 k's each
        float a = 0.f;
        const int k0 = kc * 44;
        #pragma unroll 4
        for (int kk = k0; kk < k0 + 44; ++kk) a += flat[kk] * lW1[kk * 128 + f];
        atomicAdd(&hlin[f], a);
    }
    __syncthreads();

    // ---------------- ReLU -> Linear 128->1 -> sigmoid ----------------
    if (t < 128) {
        float p = fmaxf(hlin[t], 0.f) * lW2[t];
        #pragma unroll
        for (int off = 32; off > 0; off >>= 1) p += __shfl_down(p, off);
        if ((t & 63) == 0) red[t >> 6] = p;
    }
    __syncthreads();
    if (t == 0) {
        const float z = red[0] + red[1] + lb2[0];
        out[g] = 1.f / (1.f + expf(-z));
    }
}

extern "C" void kernel_launch(void* const* d_in, const int* in_sizes, int n_in,
                              void* d_out, int out_size, void* d_ws, size_t ws_size,
                              hipStream_t stream) {
    (void)in_sizes; (void)n_in; (void)out_size; (void)d_ws; (void)ws_size;
    const float* x   = (const float*)d_in[0];
    const int*   ei  = (const int*)d_in[1];
    // d_in[2] = batch (unused; batch == node/200 by construction)
    const float* W1  = (const float*)d_in[3];  const float* b1  = (const float*)d_in[4];
    const float* W2  = (const float*)d_in[5];  const float* b2  = (const float*)d_in[6];
    const float* W3  = (const float*)d_in[7];  const float* b3  = (const float*)d_in[8];
    const float* W4  = (const float*)d_in[9];  const float* b4  = (const float*)d_in[10];
    const float* cW1 = (const float*)d_in[11]; const float* cb1 = (const float*)d_in[12];
    const float* cW2 = (const float*)d_in[13]; const float* cb2 = (const float*)d_in[14];
    const float* lW1 = (const float*)d_in[15]; const float* lb1 = (const float*)d_in[16];
    const float* lW2 = (const float*)d_in[17]; const float* lb2 = (const float*)d_in[18];
    float* out = (float*)d_out;

    // Opt in to >64KB dynamic LDS (gfx950 has 160 KiB/CU). Idempotent, host-side.
    hipFuncSetAttribute((const void*)dgcnn_kernel,
                        hipFuncAttributeMaxDynamicSharedMemorySize, SMEM_BYTES);

    dgcnn_kernel<<<GRID, TPB, SMEM_BYTES, stream>>>(
        x, ei, W1, b1, W2, b2, W3, b3, W4, b4,
        cW1, cb1, cW2, cb2, lW1, lb1, lW2, lb2, out);
}